// Round 9
// baseline (266.847 us; speedup 1.0000x reference)
//
#include <hip/hip_runtime.h>

#define B_SZ 1024
#define H_SZ 2048
#define E_SZ 1024

typedef float  f32x4 __attribute__((ext_vector_type(4)));
typedef short  s16x8 __attribute__((ext_vector_type(8)));

__device__ __forceinline__ unsigned short f2bf(float f) {
    unsigned u = __float_as_uint(f);
    u = u + 0x7fffu + ((u >> 16) & 1u);   // RNE
    return (unsigned short)(u >> 16);
}
__device__ __forceinline__ float bf2f(unsigned short s) {
    return __uint_as_float(((unsigned)s) << 16);
}
__device__ __forceinline__ float sigm(float v) {
    return 1.0f / (1.0f + __expf(-v));
}

__device__ __forceinline__ void gll(const unsigned short* g, unsigned short* l) {
    __builtin_amdgcn_global_load_lds(
        (const __attribute__((address_space(1))) unsigned int*)g,
        (__attribute__((address_space(3))) unsigned int*)l, 16, 0, 0);
}

// ---------------------------------------------------------------- cast pass
// x, h, 8 gate weights, Why (174 MB one-pass traffic).
struct CastArgs {
    const float*    src[11];
    unsigned short* dst[11];
    int             n[11];
};

__global__ __launch_bounds__(256) void cast_kernel(CastArgs a) {
    const int arr = blockIdx.y;
    const int n = a.n[arr];
    const float* __restrict__ s = a.src[arr];
    unsigned short* __restrict__ d = a.dst[arr];
    const int stride = gridDim.x * 256 * 4;
    for (int i = (blockIdx.x * 256 + threadIdx.x) * 4; i < n; i += stride) {
        float4 v = *(const float4*)(s + i);
        ushort4 o;
        o.x = f2bf(v.x); o.y = f2bf(v.y); o.z = f2bf(v.z); o.w = f2bf(v.w);
        *(ushort4*)(d + i) = o;
    }
}

// ------------- BM=64 bf16 GEMM core, 4-gate B packing, BK=64 --------------
// Same LDS swizzle / staging / fragment / MFMA pattern as the proven R0
// core; A-tile shrunk to 64 rows (2 gll) so grid=1024 -> 4 blocks/CU
// (m114 drain-hiding needs co-resident partners; R8 had only 2).
__device__ __forceinline__ void gemm_gates4_m64(
    const unsigned short* __restrict__ A,
    const unsigned short* __restrict__ W0,
    const unsigned short* __restrict__ W1,
    const unsigned short* __restrict__ W2,
    const unsigned short* __restrict__ W3,
    int ld, int kLen, int m0, int n0h,
    unsigned short* lA, unsigned short* lB,
    f32x4 acc[2][4], int t)
{
    const int lane = t & 63;
    const int w    = t >> 6;
    const int wr   = (w >> 1) << 5;   // 0,32 : wave row offset in 64-tile
    const int wc   = (w & 1) << 6;    // 0,64 : wave col offset in 128 (4x32)
    const int lr   = lane & 15;
    const int q4   = lane >> 4;       // 0..3

    // staging: chunk c = t (+256) -> row = c>>3, colblk = t&7 (swizzled).
    const int srow = t >> 3;                              // 0..31
    const int scol = ((t & 7) ^ (srow & 7)) << 3;         // swizzled col
    const unsigned short* gA = A + (size_t)(m0 + srow) * ld + scol;
    const size_t st32 = (size_t)32 * ld;
    const size_t boff = (size_t)(n0h + srow) * ld + scol;
    const unsigned short* gB0 = W0 + boff;
    const unsigned short* gB1 = W1 + boff;
    const unsigned short* gB2 = W2 + boff;
    const unsigned short* gB3 = W3 + boff;

    const int cb0 = ((q4    ) ^ (lr & 7)) << 3;
    const int cb1 = ((4 + q4) ^ (lr & 7)) << 3;

    for (int k0 = 0; k0 < kLen; k0 += 64) {
        gll(gA + k0,        lA + t * 8);
        gll(gA + k0 + st32, lA + (t + 256) * 8);
        gll(gB0 + k0, lB + t * 8);
        gll(gB1 + k0, lB + (t + 256) * 8);
        gll(gB2 + k0, lB + (t + 512) * 8);
        gll(gB3 + k0, lB + (t + 768) * 8);
        __syncthreads();

#pragma unroll
        for (int ks = 0; ks < 2; ++ks) {
            const int cb = ks ? cb1 : cb0;
            s16x8 af[2], bfr[4];
#pragma unroll
            for (int i = 0; i < 2; ++i)
                af[i] = *(const s16x8*)(lA + (wr + i * 16 + lr) * 64 + cb);
#pragma unroll
            for (int j = 0; j < 4; ++j)
                bfr[j] = *(const s16x8*)(lB + (wc + j * 16 + lr) * 64 + cb);
#pragma unroll
            for (int i = 0; i < 2; ++i)
#pragma unroll
                for (int j = 0; j < 4; ++j)
                    acc[i][j] = __builtin_amdgcn_mfma_f32_16x16x32_bf16(
                        af[i], bfr[j], acc[i][j], 0, 0, 0);
        }
        __syncthreads();
    }
}

// --------------------------------------------- gates + cell, fused kernel
// Block = 64 batch rows x (32 H-cols x 4 gates). Grid 16m x 64n = 1024
// blocks, 24KB LDS, __launch_bounds__(256,4) -> 4 blocks/CU.
struct GatesCellArgs {
    const unsigned short *Xb, *Hb, *Wxb, *Whb;
    const float *bias[4];
    const float *cin;
    float *c_out, *h_out;
    unsigned short *HnB;
};

__global__ __launch_bounds__(256, 4) void gates_cell_kernel(GatesCellArgs a) {
    __shared__ unsigned short smem[12288];    // lA 4K | lB 8K; then exchange
    unsigned short* lA = smem;
    unsigned short* lB = smem + 4096;

    const int t   = threadIdx.x;
    const int b   = blockIdx.x;
    const int xcd = b & 7;
    const int i_  = b >> 3;                 // 0..127 within XCD
    const int nt  = xcd * 8 + (i_ >> 4);    // 0..63 n-tile (32 H-cols)
    const int m0  = (i_ & 15) * 64;
    const int n0h = nt * 32;

    const size_t HE = (size_t)H_SZ * E_SZ, HH = (size_t)H_SZ * H_SZ;

    f32x4 acc[2][4] = {};
    gemm_gates4_m64(a.Xb, a.Wxb, a.Wxb + HE, a.Wxb + 2 * HE, a.Wxb + 3 * HE,
                    E_SZ, E_SZ, m0, n0h, lA, lB, acc, t);
    gemm_gates4_m64(a.Hb, a.Whb, a.Whb + HH, a.Whb + 2 * HH, a.Whb + 3 * HH,
                    H_SZ, H_SZ, m0, n0h, lA, lB, acc, t);

    // ---- epilogue 1: bias + activation -> LDS exchange [row64][col128]
    const int lane = t & 63, w = t >> 6;
    const int wr = (w >> 1) << 5, wc = (w & 1) << 6;
    const int lr = lane & 15, rq = (lane >> 4) << 2;
#pragma unroll
    for (int j = 0; j < 4; ++j) {
        const int col = wc + j * 16 + lr;       // 0..127 block-N
        const int q   = col >> 5;               // gate (wave-uniform per j)
        const float bv = a.bias[q][n0h + (col & 31)];
#pragma unroll
        for (int i = 0; i < 2; ++i) {
#pragma unroll
            for (int r = 0; r < 4; ++r) {
                const int row = wr + i * 16 + rq + r;
                const float v = acc[i][j][r] + bv;
                const float act = (q == 1) ? tanhf(v) : sigm(v);
                smem[row * 128 + col] = f2bf(act);
            }
        }
    }
    __syncthreads();

    // ---- epilogue 2: cell update, 8 elems/thread (row = t>>2)
    {
        const int row = t >> 2;          // 0..63
        const int hc  = (t & 3) * 8;     // 0..24 within the 32 H-cols
        const unsigned short* ex = smem + row * 128;
        s16x8 iv8 = *(const s16x8*)(ex + hc);
        s16x8 gv8 = *(const s16x8*)(ex + 32 + hc);
        s16x8 fv8 = *(const s16x8*)(ex + 64 + hc);
        s16x8 ov8 = *(const s16x8*)(ex + 96 + hc);

        const size_t gidx = (size_t)(m0 + row) * H_SZ + n0h + hc;
        float cn[8], hn[8];
#pragma unroll
        for (int k = 0; k < 8; ++k) {
            const float iv = bf2f((unsigned short)iv8[k]);
            const float gv = bf2f((unsigned short)gv8[k]);
            const float fv = bf2f((unsigned short)fv8[k]);
            const float ov = bf2f((unsigned short)ov8[k]);
            const float cv = a.cin[gidx + k];
            cn[k] = fv * cv + iv * gv;
            hn[k] = ov * cn[k];
        }
#pragma unroll
        for (int k = 0; k < 8; k += 4) {
            *(float4*)(a.c_out + gidx + k) = make_float4(cn[k], cn[k+1], cn[k+2], cn[k+3]);
            *(float4*)(a.h_out + gidx + k) = make_float4(hn[k], hn[k+1], hn[k+2], hn[k+3]);
            ushort4 hb;
            hb.x = f2bf(hn[k]);     hb.y = f2bf(hn[k+1]);
            hb.z = f2bf(hn[k+2]);   hb.w = f2bf(hn[k+3]);
            *(ushort4*)(a.HnB + gidx + k) = hb;
        }
    }
}

// ----------------------------------------- bf16 GEMM core, BK=64 (R0 exact)
__device__ __forceinline__ void gemm_accum64(
    const unsigned short* __restrict__ A,
    const unsigned short* __restrict__ W,
    int ld, int kLen, int m0, int n0,
    unsigned short* lA, unsigned short* lB,
    f32x4 acc[4][4], int t)
{
    const int lane = t & 63;
    const int w    = t >> 6;
    const int wr   = (w >> 1) << 6;
    const int wc   = (w & 1) << 6;
    const int lr   = lane & 15;
    const int q4   = lane >> 4;

    const int srow = t >> 3;
    const int scol = ((t & 7) ^ (srow & 7)) << 3;
    const unsigned short* gA = A + (size_t)(m0 + srow) * ld + scol;
    const unsigned short* gB = W + (size_t)(n0 + srow) * ld + scol;
    const size_t st32 = (size_t)32 * ld;

    const int cb0 = ((q4    ) ^ (lr & 7)) << 3;
    const int cb1 = ((4 + q4) ^ (lr & 7)) << 3;

    for (int k0 = 0; k0 < kLen; k0 += 64) {
#pragma unroll
        for (int p = 0; p < 4; ++p)
            gll(gA + k0 + p * st32, lA + (t + 256 * p) * 8);
#pragma unroll
        for (int p = 0; p < 4; ++p)
            gll(gB + k0 + p * st32, lB + (t + 256 * p) * 8);
        __syncthreads();

#pragma unroll
        for (int ks = 0; ks < 2; ++ks) {
            const int cb = ks ? cb1 : cb0;
            s16x8 af[4], bfr[4];
#pragma unroll
            for (int i = 0; i < 4; ++i)
                af[i] = *(const s16x8*)(lA + (wr + i * 16 + lr) * 64 + cb);
#pragma unroll
            for (int j = 0; j < 4; ++j)
                bfr[j] = *(const s16x8*)(lB + (wc + j * 16 + lr) * 64 + cb);
#pragma unroll
            for (int i = 0; i < 4; ++i)
#pragma unroll
                for (int j = 0; j < 4; ++j)
                    acc[i][j] = __builtin_amdgcn_mfma_f32_16x16x32_bf16(
                        af[i], bfr[j], acc[i][j], 0, 0, 0);
        }
        __syncthreads();
    }
}

// ------------------------------- y GEMM, bf16 Why, split-K by 8 (2/CU) ----
__global__ __launch_bounds__(256, 2) void y_split_kernel(
    const unsigned short* __restrict__ Hn,
    const unsigned short* __restrict__ Wy,
    float* __restrict__ part)
{
    __shared__ unsigned short lA[128 * 64];
    __shared__ unsigned short lB[128 * 64];
    const int t   = threadIdx.x;
    const int b   = blockIdx.x;
    const int xcd = b & 7;
    const int i_  = b >> 3;                 // 0..63 within XCD
    const int ns  = xcd * 8 + (i_ >> 3);    // 0..63: (n-tile, split)
    const int m0  = (i_ & 7) * 128;
    const int n0  = (ns >> 3) * 128;
    const int s   = ns & 7;

    f32x4 acc[4][4] = {};
    gemm_accum64(Hn + s * 256, Wy + s * 256, H_SZ, 256, m0, n0, lA, lB, acc, t);

    const int lane = t & 63, w = t >> 6;
    const int wr = (w >> 1) << 6, wc = (w & 1) << 6;
    const int lr = lane & 15, rq = (lane >> 4) << 2;
    float* P = part + (size_t)s * B_SZ * E_SZ;
#pragma unroll
    for (int i = 0; i < 4; ++i) {
#pragma unroll
        for (int j = 0; j < 4; ++j) {
            const int n = n0 + wc + j * 16 + lr;
#pragma unroll
            for (int r = 0; r < 4; ++r) {
                const int m = m0 + wr + i * 16 + rq + r;
                P[(size_t)m * E_SZ + n] = acc[i][j][r];
            }
        }
    }
}

__global__ __launch_bounds__(256) void y_reduce_kernel(
    const float* __restrict__ part, const float* __restrict__ by,
    float* __restrict__ yout)
{
    const size_t BE = (size_t)B_SZ * E_SZ;
    const int idx = (blockIdx.x * 256 + threadIdx.x) * 4;
    float4 s0 = *(const float4*)(part + idx);
#pragma unroll
    for (int s = 1; s < 8; ++s) {
        float4 p = *(const float4*)(part + (size_t)s * BE + idx);
        s0.x += p.x; s0.y += p.y; s0.z += p.z; s0.w += p.w;
    }
    const int col = idx & (E_SZ - 1);
    float4 bv = *(const float4*)(by + col);
    float4 o;
    o.x = tanhf(s0.x + bv.x);
    o.y = tanhf(s0.y + bv.y);
    o.z = tanhf(s0.z + bv.z);
    o.w = tanhf(s0.w + bv.w);
    *(float4*)(yout + idx) = o;
}

// ---------------------------------------------------------------- launch
extern "C" void kernel_launch(void* const* d_in, const int* in_sizes, int n_in,
                              void* d_out, int out_size, void* d_ws, size_t ws_size,
                              hipStream_t stream) {
    const float* x   = (const float*)d_in[0];
    const float* c   = (const float*)d_in[1];
    const float* h   = (const float*)d_in[2];
    const float* Wxi = (const float*)d_in[3];
    const float* Whi = (const float*)d_in[4];
    const float* Bi  = (const float*)d_in[5];
    const float* Wxg = (const float*)d_in[6];
    const float* Whg = (const float*)d_in[7];
    const float* Bg  = (const float*)d_in[8];
    const float* Wxf = (const float*)d_in[9];
    const float* Whf = (const float*)d_in[10];
    const float* Bf  = (const float*)d_in[11];
    const float* Wxo = (const float*)d_in[12];
    const float* Who = (const float*)d_in[13];
    const float* Bo  = (const float*)d_in[14];
    const float* Why = (const float*)d_in[15];
    const float* By  = (const float*)d_in[16];

    const size_t BE = (size_t)B_SZ * E_SZ, BH = (size_t)B_SZ * H_SZ;
    const size_t HE = (size_t)H_SZ * E_SZ, HH = (size_t)H_SZ * H_SZ;
    const size_t EH = (size_t)E_SZ * H_SZ;

    unsigned short* ws   = (unsigned short*)d_ws;
    unsigned short* Xb   = ws;                 // BE bf16
    unsigned short* Hb   = Xb + BE;            // BH bf16
    unsigned short* Wxb  = Hb + BH;            // 4*HE bf16 (dead after gates)
    unsigned short* Whb  = Wxb + 4 * HE;       // 4*HH bf16 (dead after gates)
    unsigned short* Whyb = Whb + 4 * HH;       // EH bf16
    unsigned short* HnB  = Whyb + EH;          // BH bf16
    float*          ypart = (float*)Wxb;       // 8*BE f32 aliases dead weights

    CastArgs ca;
    ca.src[0]  = x;   ca.dst[0]  = Xb;          ca.n[0]  = (int)BE;
    ca.src[1]  = h;   ca.dst[1]  = Hb;          ca.n[1]  = (int)BH;
    ca.src[2]  = Wxi; ca.dst[2]  = Wxb;         ca.n[2]  = (int)HE;
    ca.src[3]  = Wxg; ca.dst[3]  = Wxb + HE;    ca.n[3]  = (int)HE;
    ca.src[4]  = Wxf; ca.dst[4]  = Wxb + 2*HE;  ca.n[4]  = (int)HE;
    ca.src[5]  = Wxo; ca.dst[5]  = Wxb + 3*HE;  ca.n[5]  = (int)HE;
    ca.src[6]  = Whi; ca.dst[6]  = Whb;         ca.n[6]  = (int)HH;
    ca.src[7]  = Whg; ca.dst[7]  = Whb + HH;    ca.n[7]  = (int)HH;
    ca.src[8]  = Whf; ca.dst[8]  = Whb + 2*HH;  ca.n[8]  = (int)HH;
    ca.src[9]  = Who; ca.dst[9]  = Whb + 3*HH;  ca.n[9]  = (int)HH;
    ca.src[10] = Why; ca.dst[10] = Whyb;        ca.n[10] = (int)EH;
    hipLaunchKernelGGL(cast_kernel, dim3(512, 11), dim3(256), 0, stream, ca);

    float* y_out = (float*)d_out;
    float* c_out = y_out + BE;
    float* h_out = c_out + BH;

    GatesCellArgs ga;
    ga.Xb = Xb; ga.Hb = Hb; ga.Wxb = Wxb; ga.Whb = Whb;
    ga.bias[0] = Bi; ga.bias[1] = Bg; ga.bias[2] = Bf; ga.bias[3] = Bo;
    ga.cin = c; ga.c_out = c_out; ga.h_out = h_out; ga.HnB = HnB;
    hipLaunchKernelGGL(gates_cell_kernel, dim3(1024), dim3(256), 0, stream, ga);

    hipLaunchKernelGGL(y_split_kernel, dim3(512), dim3(256), 0, stream,
                       HnB, Whyb, ypart);
    hipLaunchKernelGGL(y_reduce_kernel, dim3((unsigned)(BE / 1024)), dim3(256), 0, stream,
                       ypart, By, y_out);
}